// Round 5
// baseline (146.934 us; speedup 1.0000x reference)
//
#include <hip/hip_runtime.h>

// ---------------------------------------------------------------------------
// MultiHeadAttention: x(2,2048,768) -> QKV proj -> 12-head causal attn -> proj
// Round 16: attn is LDS-read-BW-bound (4 waves x (16K K + 16K V) = 128 KB /
// block-iter ~= 3072 cyc of the ~3600 cyc iter; explains R4 pipeline null).
// Rewrite attn on 32x32x16 MFMA (16 FLOP/LDS-byte vs 8): wave w owns
// (qh=w&1)*32 q-rows x (kh=w>>1)*64 k-half -> each wave reads only half of
// K and V => 64 KB/block-iter. O kh-partials combined once per segment via
// LDS. P feeds PV straight from packed softmax regs under the R13-validated
// permuted-k mapping (V read as 2x b64 at matching chunks); no cross-lane
// ops; normalization needs no shuffles (lane's O-values share one q).
// Staging loop reverted to R3 2-barrier form (R4 pipeline regressed).
// gemm1/gemm2/prep/fixup identical to R3.
// ---------------------------------------------------------------------------

typedef float f32x4 __attribute__((ext_vector_type(4)));
typedef float f32x16 __attribute__((ext_vector_type(16)));
typedef __bf16 bf16x8 __attribute__((ext_vector_type(8)));
typedef unsigned int u32x4 __attribute__((ext_vector_type(4)));

#define D_MODEL 768
#define F3 2304
#define NHEADS 12
#define HEAD 64
#define BB 2
#define TT 2048
#define MROWS (BB*TT)      // 4096
#define KDIM 768
#define LOG2E 1.44269504f
#define NX (MROWS*D_MODEL)
#define NW1 (F3*KDIM)
#define NW2 (D_MODEL*KDIM)
#define NHT 16                        // heavy q-tiles per head (qt 16..31)
#define NOF (BB*NHEADS*NHT*64*64)     // partial-O floats per producer
#define NLF (BB*NHEADS*NHT*64)        // partial-l floats per producer

__device__ __forceinline__ unsigned short f2bf(float f) {
    unsigned int u = __float_as_uint(f);
    u += 0x7fffu + ((u >> 16) & 1u);
    return (unsigned short)(u >> 16);
}
__device__ __forceinline__ unsigned int pack2bf(float a, float b) {
    unsigned int ua = __float_as_uint(a), ub = __float_as_uint(b);
    ua += 0x7fffu + ((ua >> 16) & 1u);
    ub += 0x7fffu + ((ub >> 16) & 1u);
    return (ua >> 16) | (ub & 0xffff0000u);
}

__device__ __forceinline__ void async_copy16(unsigned short* lds, const unsigned short* g) {
    __builtin_amdgcn_global_load_lds(
        (const __attribute__((address_space(1))) unsigned int*)(const void*)g,
        (__attribute__((address_space(3))) unsigned int*)(void*)lds,
        16, 0, 0);
}

// ---- fused prep: fp32 -> bf16 for x, W1, W2 (4 elems/thread) --------------
__global__ void prep(const float* __restrict__ x, const float* __restrict__ W1,
                     const float* __restrict__ W2, unsigned short* __restrict__ xb,
                     unsigned short* __restrict__ w1b, unsigned short* __restrict__ w2b) {
    const int i4 = (blockIdx.x * blockDim.x + threadIdx.x) * 4;
    const float* src; unsigned short* dst; int off;
    if (i4 < NX)                  { src = x;  dst = xb;  off = i4; }
    else if (i4 < NX + NW1)       { src = W1; dst = w1b; off = i4 - NX; }
    else if (i4 < NX + NW1 + NW2) { src = W2; dst = w2b; off = i4 - NX - NW1; }
    else return;
    float4 v = *(const float4*)(src + off);
    uint2 o;
    o.x = pack2bf(v.x, v.y);
    o.y = pack2bf(v.z, v.w);
    *(uint2*)(dst + off) = o;
}

// ---- GEMM1: 128x96 tile, 768 blocks = 3/CU exact. C = A Bw^T --------------
// XCD band swizzle: xcd = F&7 owns an 8(m) x 12(n) tile band.
__global__ __launch_bounds__(256, 4) void gemm1(
    const unsigned short* __restrict__ A, const unsigned short* __restrict__ Bw,
    const float* __restrict__ bias, int K,
    unsigned short* __restrict__ Qb, unsigned short* __restrict__ Kb,
    unsigned short* __restrict__ VT)
{
    __shared__ unsigned short As[128*64];    // 16 KB
    __shared__ unsigned short Bs[96*64];     // 12 KB
    const int tid  = threadIdx.x;
    const int wave = tid >> 6;
    const int lane = tid & 63;
    const int quad = lane >> 4;
    const int l16  = lane & 15;

    const int F   = blockIdx.x;
    const int xcd = F & 7;
    const int idx = F >> 3;                  // 0..95
    const int bm  = (xcd & 3) * 8 + (idx & 7);    // 0..31
    const int bn  = (xcd >> 2) * 12 + (idx >> 3); // 0..23
    const int m0  = bm * 128;
    const int n0  = bn * 96;
    const int seg = bn >> 3;                 // 0=Q 1=K 2=V (96*8=768)

    const int wm = (wave >> 1) * 64;
    const int wn = (wave & 1) * 48;

    f32x4 acc[4][3] = {};

    const unsigned short* Ablk = A + (size_t)m0 * K;
    const unsigned short* Bblk = Bw + (size_t)n0 * K;
    const int srow = tid >> 3;                            // 0..31
    const int scol = ((tid & 7) ^ (srow & 7)) * 8;        // swizzled source chunk

    for (int k0 = 0; k0 < K; k0 += 64) {
        #pragma unroll
        for (int r = 0; r < 4; ++r)      // A rows r*32 + srow (128 rows)
            async_copy16(As + r*2048 + tid*8,
                         Ablk + (size_t)(r*32 + srow) * K + k0 + scol);
        #pragma unroll
        for (int r = 0; r < 3; ++r)      // B rows r*32 + srow (96 rows)
            async_copy16(Bs + r*2048 + tid*8,
                         Bblk + (size_t)(r*32 + srow) * K + k0 + scol);
        asm volatile("s_waitcnt vmcnt(0)" ::: "memory");
        __syncthreads();

        #pragma unroll
        for (int kc2 = 0; kc2 < 2; ++kc2) {
            const int pos = ((kc2*4 + quad) ^ (l16 & 7)) * 8;   // swizzled read
            bf16x8 a[4], b[3];
            #pragma unroll
            for (int i = 0; i < 4; ++i)
                a[i] = *(const bf16x8*)(As + (wm + i*16 + l16)*64 + pos);
            #pragma unroll
            for (int j = 0; j < 3; ++j)
                b[j] = *(const bf16x8*)(Bs + (wn + j*16 + l16)*64 + pos);
            #pragma unroll
            for (int i = 0; i < 4; ++i)
                #pragma unroll
                for (int j = 0; j < 3; ++j)
                    acc[i][j] = __builtin_amdgcn_mfma_f32_16x16x32_bf16(a[i], b[j], acc[i][j], 0, 0, 0);
        }
        __syncthreads();
    }

    if (seg < 2) {                           // Q or K: (b,h,t,d) scalar stores
        #pragma unroll
        for (int j = 0; j < 3; ++j) {
            const int n = n0 + wn + j*16 + l16;
            const float bv = bias[n];
            const int f = n - seg * 768;
            const int h = f >> 6, d = f & 63;
            #pragma unroll
            for (int i = 0; i < 4; ++i)
                #pragma unroll
                for (int r = 0; r < 4; ++r) {
                    const int m = m0 + wm + i*16 + quad*4 + r;
                    const int b = m >> 11, t = m & 2047;
                    const size_t idxq = (((size_t)(b*NHEADS + h)) * TT + t) * HEAD + d;
                    const float v = acc[i][j][r] + bv;
                    if (seg == 0) Qb[idxq] = f2bf(v * (0.125f * LOG2E));
                    else          Kb[idxq] = f2bf(v);
                }
        }
    } else {                                 // V: write V^T (b,h,d,t), 8B packed
        #pragma unroll
        for (int j = 0; j < 3; ++j) {
            const int n = n0 + wn + j*16 + l16;
            const float bv = bias[n];
            const int f = n - 1536;
            const int h = f >> 6, d = f & 63;
            #pragma unroll
            for (int i = 0; i < 4; ++i) {
                const int m = m0 + wm + i*16 + quad*4;
                const int b = m >> 11, t = m & 2047;
                uint2 pk;
                pk.x = pack2bf(acc[i][j][0] + bv, acc[i][j][1] + bv);
                pk.y = pack2bf(acc[i][j][2] + bv, acc[i][j][3] + bv);
                *(uint2*)(VT + ((size_t)(b*NHEADS + h) * HEAD + d) * TT + t) = pk;
            }
        }
    }
}

// ---- GEMM2: 64x96 tile, 512 blocks = 2/CU exact. fp32 out + bias ----------
// XCD band swizzle: xcd owns a 16(m) x 4(n) tile band.
__global__ __launch_bounds__(256, 4) void gemm2(
    const unsigned short* __restrict__ A, const unsigned short* __restrict__ Bw,
    const float* __restrict__ bias, int K, float* __restrict__ Cout)
{
    __shared__ unsigned short As[64*64];     // 8 KB
    __shared__ unsigned short Bs[96*64];     // 12 KB
    const int tid  = threadIdx.x;
    const int wave = tid >> 6;
    const int lane = tid & 63;
    const int quad = lane >> 4;
    const int l16  = lane & 15;

    const int F   = blockIdx.x;
    const int xcd = F & 7;
    const int idx = F >> 3;                  // 0..63
    const int m0  = ((xcd & 3) * 16 + (idx & 15)) * 64;   // 64 m-tiles
    const int n0  = ((xcd >> 2) * 4 + (idx >> 4)) * 96;   // 8 n-tiles

    const int wm = (wave >> 1) * 32;
    const int wn = (wave & 1) * 48;

    f32x4 acc[2][3] = {};

    const unsigned short* Ablk = A + (size_t)m0 * K;
    const unsigned short* Bblk = Bw + (size_t)n0 * K;
    const int srow = tid >> 3;                            // 0..31
    const int scol = ((tid & 7) ^ (srow & 7)) * 8;        // swizzled source chunk

    for (int k0 = 0; k0 < K; k0 += 64) {
        #pragma unroll
        for (int r = 0; r < 2; ++r)      // A rows r*32 + srow (64 rows)
            async_copy16(As + r*2048 + tid*8,
                         Ablk + (size_t)(r*32 + srow) * K + k0 + scol);
        #pragma unroll
        for (int r = 0; r < 3; ++r)      // B rows r*32 + srow (96 rows)
            async_copy16(Bs + r*2048 + tid*8,
                         Bblk + (size_t)(r*32 + srow) * K + k0 + scol);
        asm volatile("s_waitcnt vmcnt(0)" ::: "memory");
        __syncthreads();

        #pragma unroll
        for (int kc2 = 0; kc2 < 2; ++kc2) {
            const int pos = ((kc2*4 + quad) ^ (l16 & 7)) * 8;
            bf16x8 a[2], b[3];
            #pragma unroll
            for (int i = 0; i < 2; ++i)
                a[i] = *(const bf16x8*)(As + (wm + i*16 + l16)*64 + pos);
            #pragma unroll
            for (int j = 0; j < 3; ++j)
                b[j] = *(const bf16x8*)(Bs + (wn + j*16 + l16)*64 + pos);
            #pragma unroll
            for (int i = 0; i < 2; ++i)
                #pragma unroll
                for (int j = 0; j < 3; ++j)
                    acc[i][j] = __builtin_amdgcn_mfma_f32_16x16x32_bf16(a[i], b[j], acc[i][j], 0, 0, 0);
        }
        __syncthreads();
    }

    #pragma unroll
    for (int j = 0; j < 3; ++j) {
        const int n = n0 + wn + j*16 + l16;
        const float bv = bias[n];
        #pragma unroll
        for (int i = 0; i < 2; ++i)
            #pragma unroll
            for (int r = 0; r < 4; ++r) {
                const int m = m0 + wm + i*16 + quad*4 + r;
                Cout[(size_t)m * D_MODEL + n] = acc[i][j][r] + bv;
            }
    }
}

// ---- flash attention (causal), 32x32x16 MFMA, kh-split waves --------------
// 768 blocks (XCD owns 3 heads), 32 KB LDS, 4 waves: wave w = (qh=w&1,
// kh=w>>1): 32 q-rows x 64-k half per iter. Each wave reads only its K/V
// half from LDS (64 KB/block-iter total, half of the 16x16 version).
// S^T = K Q^T via mfma(A=K-rows, B=Q): C col=lane&31=q, row R=(e&3)+8*(e>>2)
// +4*hi = k. P stays in regs; PV uses permuted-k mapping (slot j of half hi
// carries k = 4hi+j / 8+4hi+j per 16-chunk) with V A-frags read as 2x b64 at
// the matching swizzled chunks. O^T kh-partials combined via LDS per segment.
__global__ __launch_bounds__(256, 3) void attn(
    const unsigned short* __restrict__ Qb, const unsigned short* __restrict__ Kb,
    const unsigned short* __restrict__ VT, unsigned short* __restrict__ Ob,
    float* __restrict__ OfA, float* __restrict__ OfB,
    float* __restrict__ LfA, float* __restrict__ LfB)
{
    __shared__ unsigned short Ks[128*64];   // 16 KB
    __shared__ unsigned short Vt[64*128];   // 16 KB (doubles as O-combine buf)

    const int tid  = threadIdx.x;
    const int wave = tid >> 6;
    const int lane = tid & 63;
    const int hi   = lane >> 5;
    const int l32  = lane & 31;
    const int qh   = wave & 1;              // q 32-row half
    const int kh   = wave >> 1;             // k 64 half

    const int F    = blockIdx.y * 32 + blockIdx.x;   // flat dispatch id
    const int xcd  = F & 7;
    const int slot = F >> 3;                          // 0..95
    const int bh   = xcd * 3 + (slot >> 5);           // 3 heads per XCD
    const int j    = slot & 31;                       // job id 0..31

    const int i    = j & 15;
    const bool isA = (j < 16);
    const int half = i >> 1;             // 0..7
    const int split = 8 - half;          // heavy-tile kts owned by job A
    const size_t hbase = (size_t)bh * TT * HEAD;

    // DMA source offsets (thread tid fills LDS chunk tid*8):
    const int krow = tid >> 3;
    const int kchunk = ((tid & 7) ^ (krow & 7)) * 8;
    const int vrow = tid >> 4;
    const int vchunk = ((tid & 15) ^ vrow) * 8;

    const int nseg = isA ? 2 : 1;
    for (int segi = 0; segi < nseg; ++segi) {
        int qt, kb, ke; bool full;
        if (isA) {
            if (segi == 0) { qt = i;      kb = 0;     ke = half + 1;  full = true;  }
            else           { qt = 31 - i; kb = 0;     ke = split;     full = false; }
        } else             { qt = 31 - i; kb = split; ke = 16 - half; full = false; }
        const bool domask = (ke == (qt >> 1) + 1);   // segment ends at diagonal
        const int qg = qt*64 + qh*32 + l32;          // this lane's global q row

        // Q B-frags: positional d = dk*16 + hi*8 + {0..7}
        bf16x8 qreg[4];
        #pragma unroll
        for (int dk = 0; dk < 4; ++dk)
            qreg[dk] = *(const bf16x8*)(Qb + hbase + (size_t)qg * HEAD + dk*16 + hi*8);

        f32x16 oacc[2] = {};   // O^T: d = dt*32 + R, q = l32
        float lst = 0.f;

        for (int kt = kb; kt < ke; ++kt) {
            __syncthreads();   // prev iteration's consumers done with Ks/Vt

            const unsigned short* ksrc = Kb + hbase + (size_t)kt * 128 * HEAD;
            #pragma unroll
            for (int ii = 0; ii < 4; ++ii)
                async_copy16(Ks + ii*2048 + tid*8,
                             ksrc + (size_t)(ii*32 + krow) * 64 + kchunk);
            #pragma unroll
            for (int ii = 0; ii < 4; ++ii)
                async_copy16(Vt + ii*2048 + tid*8,
                             VT + hbase + (size_t)(ii*16 + vrow) * TT + kt*128 + vchunk);
            asm volatile("s_waitcnt vmcnt(0)" ::: "memory");
            __syncthreads();

            // S^T: 2 tiles of 32k x 32q; A = K rows (this wave's 64-k half)
            f32x16 s[2] = {};
            #pragma unroll
            for (int dk = 0; dk < 4; ++dk) {
                const bf16x8 bq = qreg[dk];
                #pragma unroll
                for (int nt = 0; nt < 2; ++nt) {
                    const int r = kh*64 + nt*32 + l32;
                    const bf16x8 ak = *(const bf16x8*)(Ks + r*64 + (((dk*2 + hi) ^ (r & 7)) * 8));
                    s[nt] = __builtin_amdgcn_mfma_f32_32x32x16_bf16(ak, bq, s[nt], 0, 0, 0);
                }
            }

            // causal mask: only the diagonal tile
            if (domask && kt == ke - 1) {
                const int kbase = kt*128 + kh*64;
                #pragma unroll
                for (int nt = 0; nt < 2; ++nt)
                    #pragma unroll
                    for (int e = 0; e < 16; ++e) {
                        const int kk = kbase + nt*32 + (e & 3) + 8*(e >> 2) + 4*hi;
                        if (kk > qg) s[nt][e] = -1e30f;
                    }
            }

            // softmax numerators, fixed max (log2e folded into Q); pack pairs
            float rsum = 0.f;
            unsigned int w[2][8];
            #pragma unroll
            for (int nt = 0; nt < 2; ++nt)
                #pragma unroll
                for (int e2 = 0; e2 < 8; ++e2) {
                    const float p0 = exp2f(s[nt][2*e2]);
                    const float p1 = exp2f(s[nt][2*e2 + 1]);
                    rsum += p0 + p1;
                    w[nt][e2] = pack2bf(p0, p1);
                }
            rsum += __shfl_xor(rsum, 32);   // lane^32 holds complementary rows
            lst += rsum;

            // O^T += V^T P^T. Per 16-k chunk kc: B(P) slot (hi,j) carries
            // k = 16kc + 4hi+j (j<4) / 16kc+8+4hi+(j-4); A(V) fetched to match.
            #pragma unroll
            for (int kc = 0; kc < 4; ++kc) {
                const int nt = kc >> 1, sub = kc & 1;
                u32x4 pw = {w[nt][4*sub], w[nt][4*sub+1], w[nt][4*sub+2], w[nt][4*sub+3]};
                const bf16x8 ap = __builtin_bit_cast(bf16x8, pw);
                const int g0 = kh*8 + kc*2;          // global 8-elem k-chunk
                #pragma unroll
                for (int dt = 0; dt < 2; ++dt) {
                    const int d = dt*32 + l32;
                    const unsigned short* vr = Vt + d*128;
                    const uint2 lo = *(const uint2*)(vr + ((g0     ^ (d & 15)) * 8) + hi*4);
                    const uint2 h2 = *(const uint2*)(vr + (((g0+1) ^ (d & 15)) * 8) + hi*4);
                    u32x4 vv = {lo.x, lo.y, h2.x, h2.y};
                    const bf16x8 av = __builtin_bit_cast(bf16x8, vv);
                    oacc[dt] = __builtin_amdgcn_mfma_f32_32x32x16_bf16(av, ap, oacc[dt], 0, 0, 0);
                }
            }
        }

        // ---- kh-combine via LDS (Vt free after loop) + epilogue ----
        __syncthreads();
        {
            float* Oc = (float*)Vt;     // 4096 floats, exact fit
            float* Lc = (float*)Ks;
            if (kh == 1) {
                #pragma unroll
                for (int dt = 0; dt < 2; ++dt)
                    #pragma unroll
                    for (int e = 0; e < 16; ++e)
                        Oc[qh*2048 + dt*1024 + e*64 + lane] = oacc[dt][e];
                if (lane < 32) Lc[qh*32 + lane] = lst;
            }
            __syncthreads();
            if (kh == 0) {
                #pragma unroll
                for (int dt = 0; dt < 2; ++dt)
                    #pragma unroll
                    for (int e = 0; e < 16; ++e)
                        oacc[dt][e] += Oc[qh*2048 + dt*1024 + e*64 + lane];
                lst += Lc[qh*32 + l32];

                if (full) {
                    const float linv = 1.0f / lst;   // lane's O all share q=l32
                    const int b = bh / NHEADS, h = bh % NHEADS;
                    const int m = b * TT + qg;
                    unsigned short* dst = Ob + (size_t)m * D_MODEL + h*HEAD;
                    #pragma unroll
                    for (int dt = 0; dt < 2; ++dt)
                        #pragma unroll
                        for (int q4 = 0; q4 < 4; ++q4) {
                            const int e = q4*4;
                            uint2 pk;
                            pk.x = pack2bf(oacc[dt][e]*linv,   oacc[dt][e+1]*linv);
                            pk.y = pack2bf(oacc[dt][e+2]*linv, oacc[dt][e+3]*linv);
                            *(uint2*)(dst + dt*32 + q4*8 + hi*4) = pk;
                        }
                } else {
                    const int qtl = qt - 16;
                    float* op = (isA ? OfA : OfB)
                                + (((size_t)(bh*NHT + qtl))*64 + qh*32 + l32)*64;
                    #pragma unroll
                    for (int dt = 0; dt < 2; ++dt)
                        #pragma unroll
                        for (int q4 = 0; q4 < 4; ++q4) {
                            const int e = q4*4;
                            f32x4 v = {oacc[dt][e], oacc[dt][e+1], oacc[dt][e+2], oacc[dt][e+3]};
                            *(f32x4*)(op + dt*32 + q4*8 + hi*4) = v;
                        }
                    if (lane < 32)
                        (isA ? LfA : LfB)[((size_t)(bh*NHT + qtl))*64 + qh*32 + lane] = lst;
                }
            }
        }
    }
}

// ---- fixup: sum 2 partials, normalize -> bf16 Ob --------------------------
// grid (16, 24), 256 thr: block = (heavy tile qtl, head). 16 floats/thread.
__global__ __launch_bounds__(256) void fixup(
    const float* __restrict__ OfA, const float* __restrict__ OfB,
    const float* __restrict__ LfA, const float* __restrict__ LfB,
    unsigned short* __restrict__ Ob)
{
    const int qtl = blockIdx.x;          // 0..15 -> qt = 16+qtl
    const int bh  = blockIdx.y;          // 0..23
    const int t   = threadIdx.x;
    const int r   = t >> 2;              // 0..63 q row within tile
    const int c0  = (t & 3) * 16;        // 0,16,32,48 d start
    const size_t lidx = ((size_t)(bh*NHT + qtl))*64 + r;
    const float linv = 1.0f / (LfA[lidx] + LfB[lidx]);
    const size_t base = (((size_t)(bh*NHT + qtl))*64 + r)*64 + c0;
    const float* sa = OfA + base;
    const float* sb = OfB + base;
    const int b = bh / NHEADS, h = bh % NHEADS;
    const int m = b*TT + (16 + qtl)*64 + r;
    unsigned short* dst = Ob + (size_t)m * D_MODEL + h*HEAD + c0;
    uint4 o0, o1;
    {
        f32x4 a0 = *(const f32x4*)(sa);      f32x4 b0 = *(const f32x4*)(sb);
        f32x4 a1 = *(const f32x4*)(sa + 4);  f32x4 b1 = *(const f32x4*)(sb + 4);
        f32x4 v0 = a0 + b0, v1 = a1 + b1;
        o0.x = pack2bf(v0[0]*linv, v0[1]*linv);
        o0.y = pack2bf(v0[2]*linv, v0[3]*linv);
        o0.z = pack2bf(v1[0]*linv, v1[1]*linv);
        o0.w = pack2bf(v1[2]*linv, v1[3]*linv);
    }
    {
        f32x4 a2 = *(const f32x4*)(sa + 8);  f32x4 b2 = *(const f32x4*)(sb + 8);
        f32x4 a3 = *(const f32x4*)(sa + 12); f32x4 b3 = *(const f32x4*)(sb + 12);
        f32x4 v2 = a2 + b2, v3 = a3 + b3;
        o1.x = pack2bf(v2[0]*linv, v2[1]*linv);
        o1.y = pack2bf(v2[2]*linv, v2[3]*linv);
        o1.z = pack2bf(v3[0]*linv, v3[1]*linv);
        o1.w = pack2bf(v3[2]*linv, v3[3]*linv);
    }
    *(uint4*)(dst)     = o0;
    *(uint4*)(dst + 8) = o1;
}

// ---------------------------------------------------------------------------
extern "C" void kernel_launch(void* const* d_in, const int* in_sizes, int n_in,
                              void* d_out, int out_size, void* d_ws, size_t ws_size,
                              hipStream_t stream) {
    const float* x  = (const float*)d_in[0];
    const float* W1 = (const float*)d_in[1];
    const float* b1 = (const float*)d_in[2];
    const float* W2 = (const float*)d_in[3];
    const float* b2 = (const float*)d_in[4];
    float* out = (float*)d_out;

    unsigned short* ws = (unsigned short*)d_ws;
    unsigned short* xb  = ws;                                   // 4096*768
    unsigned short* w1b = xb  + (size_t)NX;                     // 2304*768
    unsigned short* w2b = w1b + (size_t)NW1;                    // 768*768
    unsigned short* Qb  = w2b + (size_t)NW2;                    // 24*2048*64
    unsigned short* Kb  = Qb + (size_t)BB*NHEADS*TT*HEAD;
    unsigned short* VT  = Kb + (size_t)BB*NHEADS*TT*HEAD;       // (b,h,d,t)
    unsigned short* Ob  = VT + (size_t)BB*NHEADS*TT*HEAD;       // 4096*768
    float* OfA = (float*)(Ob + (size_t)NX);                     // partials A
    float* OfB = OfA + (size_t)NOF;                             // partials B
    float* LfA = OfB + (size_t)NOF;
    float* LfB = LfA + (size_t)NLF;

    prep<<<((NX + NW1 + NW2)/4 + 255)/256, 256, 0, stream>>>(
        x, W1, W2, xb, w1b, w2b);

    gemm1<<<768, 256, 0, stream>>>(
        xb, w1b, b1, KDIM, Qb, Kb, VT);

    attn<<<dim3(32, BB*NHEADS), 256, 0, stream>>>(
        Qb, Kb, VT, Ob, OfA, OfB, LfA, LfB);

    fixup<<<dim3(NHT, BB*NHEADS), 256, 0, stream>>>(OfA, OfB, LfA, LfB, Ob);

    gemm2<<<512, 256, 0, stream>>>(
        Ob, w2b, b2, KDIM, out);
}

// Round 6
// 146.630 us; speedup vs baseline: 1.0021x; 1.0021x over previous
//
#include <hip/hip_runtime.h>

// ---------------------------------------------------------------------------
// MultiHeadAttention: x(2,2048,768) -> QKV proj -> 12-head causal attn -> proj
// Round 17: EXACT-BALANCE attn, no split-KV, no fixup. At BQ=32/KV=128 the
// causal work per head is 544 = 32x17 exactly, and pairing q-tiles (t, 63-t)
// gives 17 iters for EVERY pair. 768 blocks (24 heads x 32 pair-jobs), each
// exactly 17 iterations, serial two segments. Waves k-split the 128-k tile
// (32 k each); fixed-max softmax => per-wave O/l k-partials accumulate in
// REGISTERS all segment, one LDS combine per segment (2x/job). PV uses the
// R2-validated in-register-P permuted-k mapping (one 32-k group per wave).
// Per-wave LDS reads/iter: 4 b128 + 8 b64 (4x less than R3). Partials (Of/
// Lf, 50 MB HBM) and the fixup kernel are DELETED. prep/gemm1/gemm2 = R3.
// ---------------------------------------------------------------------------

typedef float f32x4 __attribute__((ext_vector_type(4)));
typedef __bf16 bf16x8 __attribute__((ext_vector_type(8)));
typedef unsigned int u32x4 __attribute__((ext_vector_type(4)));

#define D_MODEL 768
#define F3 2304
#define NHEADS 12
#define HEAD 64
#define BB 2
#define TT 2048
#define MROWS (BB*TT)      // 4096
#define KDIM 768
#define LOG2E 1.44269504f
#define NX (MROWS*D_MODEL)
#define NW1 (F3*KDIM)
#define NW2 (D_MODEL*KDIM)

__device__ __forceinline__ unsigned short f2bf(float f) {
    unsigned int u = __float_as_uint(f);
    u += 0x7fffu + ((u >> 16) & 1u);
    return (unsigned short)(u >> 16);
}
__device__ __forceinline__ unsigned int pack2bf(float a, float b) {
    unsigned int ua = __float_as_uint(a), ub = __float_as_uint(b);
    ua += 0x7fffu + ((ua >> 16) & 1u);
    ub += 0x7fffu + ((ub >> 16) & 1u);
    return (ua >> 16) | (ub & 0xffff0000u);
}

__device__ __forceinline__ void async_copy16(unsigned short* lds, const unsigned short* g) {
    __builtin_amdgcn_global_load_lds(
        (const __attribute__((address_space(1))) unsigned int*)(const void*)g,
        (__attribute__((address_space(3))) unsigned int*)(void*)lds,
        16, 0, 0);
}

// ---- fused prep: fp32 -> bf16 for x, W1, W2 (4 elems/thread) --------------
__global__ void prep(const float* __restrict__ x, const float* __restrict__ W1,
                     const float* __restrict__ W2, unsigned short* __restrict__ xb,
                     unsigned short* __restrict__ w1b, unsigned short* __restrict__ w2b) {
    const int i4 = (blockIdx.x * blockDim.x + threadIdx.x) * 4;
    const float* src; unsigned short* dst; int off;
    if (i4 < NX)                  { src = x;  dst = xb;  off = i4; }
    else if (i4 < NX + NW1)       { src = W1; dst = w1b; off = i4 - NX; }
    else if (i4 < NX + NW1 + NW2) { src = W2; dst = w2b; off = i4 - NX - NW1; }
    else return;
    float4 v = *(const float4*)(src + off);
    uint2 o;
    o.x = pack2bf(v.x, v.y);
    o.y = pack2bf(v.z, v.w);
    *(uint2*)(dst + off) = o;
}

// ---- GEMM1: 128x96 tile, 768 blocks = 3/CU exact. C = A Bw^T --------------
// XCD band swizzle: xcd = F&7 owns an 8(m) x 12(n) tile band.
__global__ __launch_bounds__(256, 4) void gemm1(
    const unsigned short* __restrict__ A, const unsigned short* __restrict__ Bw,
    const float* __restrict__ bias, int K,
    unsigned short* __restrict__ Qb, unsigned short* __restrict__ Kb,
    unsigned short* __restrict__ VT)
{
    __shared__ unsigned short As[128*64];    // 16 KB
    __shared__ unsigned short Bs[96*64];     // 12 KB
    const int tid  = threadIdx.x;
    const int wave = tid >> 6;
    const int lane = tid & 63;
    const int quad = lane >> 4;
    const int l16  = lane & 15;

    const int F   = blockIdx.x;
    const int xcd = F & 7;
    const int idx = F >> 3;                  // 0..95
    const int bm  = (xcd & 3) * 8 + (idx & 7);    // 0..31
    const int bn  = (xcd >> 2) * 12 + (idx >> 3); // 0..23
    const int m0  = bm * 128;
    const int n0  = bn * 96;
    const int seg = bn >> 3;                 // 0=Q 1=K 2=V (96*8=768)

    const int wm = (wave >> 1) * 64;
    const int wn = (wave & 1) * 48;

    f32x4 acc[4][3] = {};

    const unsigned short* Ablk = A + (size_t)m0 * K;
    const unsigned short* Bblk = Bw + (size_t)n0 * K;
    const int srow = tid >> 3;                            // 0..31
    const int scol = ((tid & 7) ^ (srow & 7)) * 8;        // swizzled source chunk

    for (int k0 = 0; k0 < K; k0 += 64) {
        #pragma unroll
        for (int r = 0; r < 4; ++r)      // A rows r*32 + srow (128 rows)
            async_copy16(As + r*2048 + tid*8,
                         Ablk + (size_t)(r*32 + srow) * K + k0 + scol);
        #pragma unroll
        for (int r = 0; r < 3; ++r)      // B rows r*32 + srow (96 rows)
            async_copy16(Bs + r*2048 + tid*8,
                         Bblk + (size_t)(r*32 + srow) * K + k0 + scol);
        asm volatile("s_waitcnt vmcnt(0)" ::: "memory");
        __syncthreads();

        #pragma unroll
        for (int kc2 = 0; kc2 < 2; ++kc2) {
            const int pos = ((kc2*4 + quad) ^ (l16 & 7)) * 8;   // swizzled read
            bf16x8 a[4], b[3];
            #pragma unroll
            for (int i = 0; i < 4; ++i)
                a[i] = *(const bf16x8*)(As + (wm + i*16 + l16)*64 + pos);
            #pragma unroll
            for (int j = 0; j < 3; ++j)
                b[j] = *(const bf16x8*)(Bs + (wn + j*16 + l16)*64 + pos);
            #pragma unroll
            for (int i = 0; i < 4; ++i)
                #pragma unroll
                for (int j = 0; j < 3; ++j)
                    acc[i][j] = __builtin_amdgcn_mfma_f32_16x16x32_bf16(a[i], b[j], acc[i][j], 0, 0, 0);
        }
        __syncthreads();
    }

    if (seg < 2) {                           // Q or K: (b,h,t,d) scalar stores
        #pragma unroll
        for (int j = 0; j < 3; ++j) {
            const int n = n0 + wn + j*16 + l16;
            const float bv = bias[n];
            const int f = n - seg * 768;
            const int h = f >> 6, d = f & 63;
            #pragma unroll
            for (int i = 0; i < 4; ++i)
                #pragma unroll
                for (int r = 0; r < 4; ++r) {
                    const int m = m0 + wm + i*16 + quad*4 + r;
                    const int b = m >> 11, t = m & 2047;
                    const size_t idxq = (((size_t)(b*NHEADS + h)) * TT + t) * HEAD + d;
                    const float v = acc[i][j][r] + bv;
                    if (seg == 0) Qb[idxq] = f2bf(v * (0.125f * LOG2E));
                    else          Kb[idxq] = f2bf(v);
                }
        }
    } else {                                 // V: write V^T (b,h,d,t), 8B packed
        #pragma unroll
        for (int j = 0; j < 3; ++j) {
            const int n = n0 + wn + j*16 + l16;
            const float bv = bias[n];
            const int f = n - 1536;
            const int h = f >> 6, d = f & 63;
            #pragma unroll
            for (int i = 0; i < 4; ++i) {
                const int m = m0 + wm + i*16 + quad*4;
                const int b = m >> 11, t = m & 2047;
                uint2 pk;
                pk.x = pack2bf(acc[i][j][0] + bv, acc[i][j][1] + bv);
                pk.y = pack2bf(acc[i][j][2] + bv, acc[i][j][3] + bv);
                *(uint2*)(VT + ((size_t)(b*NHEADS + h) * HEAD + d) * TT + t) = pk;
            }
        }
    }
}

// ---- GEMM2: 64x96 tile, 512 blocks = 2/CU exact. fp32 out + bias ----------
// XCD band swizzle: xcd owns a 16(m) x 4(n) tile band.
__global__ __launch_bounds__(256, 4) void gemm2(
    const unsigned short* __restrict__ A, const unsigned short* __restrict__ Bw,
    const float* __restrict__ bias, int K, float* __restrict__ Cout)
{
    __shared__ unsigned short As[64*64];     // 8 KB
    __shared__ unsigned short Bs[96*64];     // 12 KB
    const int tid  = threadIdx.x;
    const int wave = tid >> 6;
    const int lane = tid & 63;
    const int quad = lane >> 4;
    const int l16  = lane & 15;

    const int F   = blockIdx.x;
    const int xcd = F & 7;
    const int idx = F >> 3;                  // 0..63
    const int m0  = ((xcd & 3) * 16 + (idx & 15)) * 64;   // 64 m-tiles
    const int n0  = ((xcd >> 2) * 4 + (idx >> 4)) * 96;   // 8 n-tiles

    const int wm = (wave >> 1) * 32;
    const int wn = (wave & 1) * 48;

    f32x4 acc[2][3] = {};

    const unsigned short* Ablk = A + (size_t)m0 * K;
    const unsigned short* Bblk = Bw + (size_t)n0 * K;
    const int srow = tid >> 3;                            // 0..31
    const int scol = ((tid & 7) ^ (srow & 7)) * 8;        // swizzled source chunk

    for (int k0 = 0; k0 < K; k0 += 64) {
        #pragma unroll
        for (int r = 0; r < 2; ++r)      // A rows r*32 + srow (64 rows)
            async_copy16(As + r*2048 + tid*8,
                         Ablk + (size_t)(r*32 + srow) * K + k0 + scol);
        #pragma unroll
        for (int r = 0; r < 3; ++r)      // B rows r*32 + srow (96 rows)
            async_copy16(Bs + r*2048 + tid*8,
                         Bblk + (size_t)(r*32 + srow) * K + k0 + scol);
        asm volatile("s_waitcnt vmcnt(0)" ::: "memory");
        __syncthreads();

        #pragma unroll
        for (int kc2 = 0; kc2 < 2; ++kc2) {
            const int pos = ((kc2*4 + quad) ^ (l16 & 7)) * 8;
            bf16x8 a[2], b[3];
            #pragma unroll
            for (int i = 0; i < 2; ++i)
                a[i] = *(const bf16x8*)(As + (wm + i*16 + l16)*64 + pos);
            #pragma unroll
            for (int j = 0; j < 3; ++j)
                b[j] = *(const bf16x8*)(Bs + (wn + j*16 + l16)*64 + pos);
            #pragma unroll
            for (int i = 0; i < 2; ++i)
                #pragma unroll
                for (int j = 0; j < 3; ++j)
                    acc[i][j] = __builtin_amdgcn_mfma_f32_16x16x32_bf16(a[i], b[j], acc[i][j], 0, 0, 0);
        }
        __syncthreads();
    }

    #pragma unroll
    for (int j = 0; j < 3; ++j) {
        const int n = n0 + wn + j*16 + l16;
        const float bv = bias[n];
        #pragma unroll
        for (int i = 0; i < 2; ++i)
            #pragma unroll
            for (int r = 0; r < 4; ++r) {
                const int m = m0 + wm + i*16 + quad*4 + r;
                Cout[(size_t)m * D_MODEL + n] = acc[i][j][r] + bv;
            }
    }
}

// ---- flash attention (causal), exact-balance pair jobs, k-split waves -----
// 768 blocks (XCD owns 3 heads), 32 KB LDS -> 3/CU. Job j: q-tiles (BQ=32)
// t=j then t=63-j, serial; 17 iters total for every j. Wave w owns k-slice
// [w*32, w*32+32) of each 128-k tile; O/l k-partials live in registers all
// segment; one LDS combine per segment. S^T = K Q^T per wave: s[n][qs] tiles,
// lane: q = qs*16+l16, k = w*32+n*16+quad*4+r. PV: in-register P (permuted-k
// A-operand), V B-frags = 2x b64 at matching swizzled chunks.
__global__ __launch_bounds__(256, 3) void attn(
    const unsigned short* __restrict__ Qb, const unsigned short* __restrict__ Kb,
    const unsigned short* __restrict__ VT, unsigned short* __restrict__ Ob)
{
    __shared__ unsigned short Ks[128*64];   // 16 KB (combine: waves 1,2 O-buf)
    __shared__ unsigned short Vt[64*128];   // 16 KB (combine: wave 3 O-buf + l)

    const int tid  = threadIdx.x;
    const int wave = tid >> 6;
    const int lane = tid & 63;
    const int quad = lane >> 4;
    const int l16  = lane & 15;

    const int F    = blockIdx.y * 32 + blockIdx.x;   // flat dispatch id
    const int xcd  = F & 7;
    const int slot = F >> 3;                          // 0..95
    const int bh   = xcd * 3 + (slot >> 5);           // 3 heads per XCD
    const int j    = slot & 31;                       // pair-job id 0..31
    const size_t hbase = (size_t)bh * TT * HEAD;

    // DMA source offsets (thread tid fills LDS chunk tid*8):
    const int krow = tid >> 3;
    const int kchunk = ((tid & 7) ^ (krow & 7)) * 8;
    const int vrow = tid >> 4;
    const int vchunk = ((tid & 15) ^ vrow) * 8;

    #pragma unroll 1
    for (int seg = 0; seg < 2; ++seg) {
        const int t   = seg ? (63 - j) : j;     // q-tile (32 rows)
        const int nkt = (t >> 2) + 1;           // KV tiles to stream
        const int q0  = t * 32;

        // Q B-frags: qreg[qs][kc2], lane l16 = q col, slots d = kc2*32+quad*8+.
        bf16x8 qreg[2][2];
        #pragma unroll
        for (int qs = 0; qs < 2; ++qs) {
            const unsigned short* qp = Qb + hbase + (size_t)(q0 + qs*16 + l16) * HEAD + quad*8;
            qreg[qs][0] = *(const bf16x8*)(qp);
            qreg[qs][1] = *(const bf16x8*)(qp + 32);
        }

        f32x4 oacc[2][4] = {};    // [qs][dt]: q = q0+qs*16+quad*4+r, d = dt*16+l16
        float lst[2] = {0.f, 0.f};

        for (int kt = 0; kt < nkt; ++kt) {
            __syncthreads();   // prev consumers (incl. prev combine) done

            const unsigned short* ksrc = Kb + hbase + (size_t)kt * 128 * HEAD;
            #pragma unroll
            for (int ii = 0; ii < 4; ++ii)
                async_copy16(Ks + ii*2048 + tid*8,
                             ksrc + (size_t)(ii*32 + krow) * 64 + kchunk);
            #pragma unroll
            for (int ii = 0; ii < 4; ++ii)
                async_copy16(Vt + ii*2048 + tid*8,
                             VT + hbase + (size_t)(ii*16 + vrow) * TT + kt*128 + vchunk);
            asm volatile("s_waitcnt vmcnt(0)" ::: "memory");
            __syncthreads();

            // S^T tiles s[n][qs]: A = K rows (wave's 32-k slice), B = Q
            f32x4 s[2][2] = {};
            #pragma unroll
            for (int kc2 = 0; kc2 < 2; ++kc2) {
                const int pos = ((kc2*4 + quad) ^ (l16 & 7)) * 8;
                #pragma unroll
                for (int n = 0; n < 2; ++n) {
                    const bf16x8 ak = *(const bf16x8*)(Ks + (wave*32 + n*16 + l16)*64 + pos);
                    #pragma unroll
                    for (int qs = 0; qs < 2; ++qs)
                        s[n][qs] = __builtin_amdgcn_mfma_f32_16x16x32_bf16(ak, qreg[qs][kc2], s[n][qs], 0, 0, 0);
                }
            }

            // causal mask: only the diagonal KV tile
            if (kt == (t >> 2)) {
                const int kq = kt*128 + wave*32 + quad*4;
                #pragma unroll
                for (int n = 0; n < 2; ++n)
                    #pragma unroll
                    for (int qs = 0; qs < 2; ++qs)
                        #pragma unroll
                        for (int r = 0; r < 4; ++r)
                            if (kq + n*16 + r > q0 + qs*16 + l16) s[n][qs][r] = -1e30f;
            }

            // softmax numerators, fixed max (log2e folded into Q); pack pairs
            uint2 pck[2][2];
            #pragma unroll
            for (int n = 0; n < 2; ++n)
                #pragma unroll
                for (int qs = 0; qs < 2; ++qs) {
                    const float p0 = exp2f(s[n][qs][0]);
                    const float p1 = exp2f(s[n][qs][1]);
                    const float p2 = exp2f(s[n][qs][2]);
                    const float p3 = exp2f(s[n][qs][3]);
                    lst[qs] += (p0 + p1) + (p2 + p3);
                    pck[n][qs].x = pack2bf(p0, p1);
                    pck[n][qs].y = pack2bf(p2, p3);
                }

            // O += P V over wave's 32-k slice. A-frag slots: j<4 -> k=4q+j,
            // j>=4 -> k=16+4q+(j-4). B(V) read to match: chunks g1, g1+2.
            bf16x8 ap[2];
            #pragma unroll
            for (int qs = 0; qs < 2; ++qs) {
                u32x4 pw = {pck[0][qs].x, pck[0][qs].y, pck[1][qs].x, pck[1][qs].y};
                ap[qs] = __builtin_bit_cast(bf16x8, pw);
            }
            const int g1 = wave*4 + (quad >> 1);
            #pragma unroll
            for (int dt = 0; dt < 4; ++dt) {
                const unsigned short* vr = Vt + (dt*16 + l16)*128;
                const int c1 = ((g1     ^ l16) * 8) + (quad & 1) * 4;
                const int c2 = (((g1+2) ^ l16) * 8) + (quad & 1) * 4;
                const uint2 lo = *(const uint2*)(vr + c1);
                const uint2 hi = *(const uint2*)(vr + c2);
                u32x4 vv = {lo.x, lo.y, hi.x, hi.y};
                const bf16x8 bv = __builtin_bit_cast(bf16x8, vv);
                #pragma unroll
                for (int qs = 0; qs < 2; ++qs)
                    oacc[qs][dt] = __builtin_amdgcn_mfma_f32_16x16x32_bf16(ap[qs], bv, oacc[qs][dt], 0, 0, 0);
            }
        }

        // cross-quad reduce l (per-lane q = qs*16+l16)
        #pragma unroll
        for (int qs = 0; qs < 2; ++qs) {
            lst[qs] += __shfl_xor(lst[qs], 16);
            lst[qs] += __shfl_xor(lst[qs], 32);
        }

        // ---- cross-wave combine via LDS (aliases Ks/Vt) + epilogue ----
        __syncthreads();   // all waves done reading Ks/Vt
        {
            float* O1 = (float*)Ks;           // wave 1
            float* O2 = (float*)Ks + 2048;    // wave 2
            float* O3 = (float*)Vt;           // wave 3
            float* Lb = (float*)Vt + 2048;    // 96 floats l-partials
            if (wave != 0) {
                float* ob = (wave == 1) ? O1 : (wave == 2) ? O2 : O3;
                #pragma unroll
                for (int qs = 0; qs < 2; ++qs)
                    #pragma unroll
                    for (int dt = 0; dt < 4; ++dt)
                        #pragma unroll
                        for (int r = 0; r < 4; ++r)
                            ob[(qs*16 + quad*4 + r)*64 + dt*16 + l16] = oacc[qs][dt][r];
                if (lane < 16) {
                    Lb[(wave-1)*32 + l16]      = lst[0];
                    Lb[(wave-1)*32 + 16 + l16] = lst[1];
                }
            }
            __syncthreads();
            if (wave == 0) {
                float linv[2], lr[2][4];
                #pragma unroll
                for (int qs = 0; qs < 2; ++qs) {
                    const float lt = lst[qs] + Lb[qs*16 + l16] + Lb[32 + qs*16 + l16]
                                             + Lb[64 + qs*16 + l16];
                    linv[qs] = 1.0f / lt;
                }
                #pragma unroll
                for (int qs = 0; qs < 2; ++qs)
                    #pragma unroll
                    for (int r = 0; r < 4; ++r)
                        lr[qs][r] = __shfl(linv[qs], quad*4 + r);
                const int b = bh / NHEADS, h = bh % NHEADS;
                #pragma unroll
                for (int qs = 0; qs < 2; ++qs)
                    #pragma unroll
                    for (int r = 0; r < 4; ++r) {
                        const int m = b * TT + q0 + qs*16 + quad*4 + r;
                        unsigned short* dst = Ob + (size_t)m * D_MODEL + h*HEAD;
                        #pragma unroll
                        for (int dt = 0; dt < 4; ++dt) {
                            const int idx = (qs*16 + quad*4 + r)*64 + dt*16 + l16;
                            const float v = oacc[qs][dt][r] + O1[idx] + O2[idx] + O3[idx];
                            dst[dt*16 + l16] = f2bf(v * lr[qs][r]);
                        }
                    }
            }
        }
    }
}

// ---------------------------------------------------------------------------
extern "C" void kernel_launch(void* const* d_in, const int* in_sizes, int n_in,
                              void* d_out, int out_size, void* d_ws, size_t ws_size,
                              hipStream_t stream) {
    const float* x  = (const float*)d_in[0];
    const float* W1 = (const float*)d_in[1];
    const float* b1 = (const float*)d_in[2];
    const float* W2 = (const float*)d_in[3];
    const float* b2 = (const float*)d_in[4];
    float* out = (float*)d_out;

    unsigned short* ws = (unsigned short*)d_ws;
    unsigned short* xb  = ws;                                   // 4096*768
    unsigned short* w1b = xb  + (size_t)NX;                     // 2304*768
    unsigned short* w2b = w1b + (size_t)NW1;                    // 768*768
    unsigned short* Qb  = w2b + (size_t)NW2;                    // 24*2048*64
    unsigned short* Kb  = Qb + (size_t)BB*NHEADS*TT*HEAD;
    unsigned short* VT  = Kb + (size_t)BB*NHEADS*TT*HEAD;       // (b,h,d,t)
    unsigned short* Ob  = VT + (size_t)BB*NHEADS*TT*HEAD;       // 4096*768

    prep<<<((NX + NW1 + NW2)/4 + 255)/256, 256, 0, stream>>>(
        x, W1, W2, xb, w1b, w2b);

    gemm1<<<768, 256, 0, stream>>>(
        xb, w1b, b1, KDIM, Qb, Kb, VT);

    attn<<<dim3(32, BB*NHEADS), 256, 0, stream>>>(Qb, Kb, VT, Ob);

    gemm2<<<512, 256, 0, stream>>>(
        Ob, w2b, b2, KDIM, out);
}